// Round 15
// baseline (119.724 us; speedup 1.0000x reference)
//
#include <hip/hip_runtime.h>
#include <hip/hip_bf16.h>

#define NB 64
#define NC 256
#define NL 2048
#define NH 8
#define KW 3
#define LP (NL - KW + 1)  // 2046
#define NCHUNK 8
#define CPC (NC / NCHUNK)  // 32 channels per chunk

typedef float v4f __attribute__((ext_vector_type(4)));

// monotonic float->uint key: order(u) == order(x)
__device__ __forceinline__ unsigned fkey(float x) {
  unsigned b = __float_as_uint(x);
  return (b & 0x80000000u) ? ~b : (b | 0x80000000u);
}

// Kernel 1 (R8-proven, verbatim): conv1d partial sums. Each thread: 4
// consecutive l outputs x 8 heads from ONE float4 load per channel
// (+shuffle halo). Grid (2, NB, NCHUNK) = 1024 blocks.
// THIS ROUND: launched TWICE (identical args, identical output) as a
// timing probe — total_dur - 92.7us = conv's true cost.
__global__ __launch_bounds__(256) void conv_partial(
    const float* __restrict__ src, const float* __restrict__ conv_w,
    float* __restrict__ part) {
  const int t = threadIdx.x;
  const int lane = t & 63;
  const int l0 = blockIdx.x * 1024 + t * 4;
  const int b = blockIdx.y;
  const int cc = blockIdx.z;
  const int c0 = cc * CPC;

  float acc[NH][4];
#pragma unroll
  for (int h = 0; h < NH; ++h)
#pragma unroll
    for (int j = 0; j < 4; ++j) acc[h][j] = 0.f;

  const float* sp = src + ((size_t)b * NC + c0) * NL + l0;
  const bool tail = (lane == 63) && (l0 + 5 < NL);
#pragma unroll 2
  for (int c = 0; c < CPC; ++c) {
    v4f v = *(const v4f*)sp;
    float e0 = 0.f, e1 = 0.f;
    if (tail) { e0 = sp[4]; e1 = sp[5]; }
    sp += NL;
    float n0 = __shfl_down(v.x, 1);
    float n1 = __shfl_down(v.y, 1);
    if (lane == 63) { n0 = e0; n1 = e1; }
    float s0 = v.x, s1 = v.y, s2 = v.z, s3 = v.w, s4 = n0, s5 = n1;
#pragma unroll
    for (int h = 0; h < NH; ++h) {
      const float* w = conv_w + (h * NC + c0 + c) * KW;  // uniform -> s_load
      const float w0 = w[0], w1 = w[1], w2 = w[2];
      acc[h][0] = fmaf(s0, w0, fmaf(s1, w1, fmaf(s2, w2, acc[h][0])));
      acc[h][1] = fmaf(s1, w0, fmaf(s2, w1, fmaf(s3, w2, acc[h][1])));
      acc[h][2] = fmaf(s2, w0, fmaf(s3, w1, fmaf(s4, w2, acc[h][2])));
      acc[h][3] = fmaf(s3, w0, fmaf(s4, w1, fmaf(s5, w2, acc[h][3])));
    }
  }
#pragma unroll
  for (int h = 0; h < NH; ++h) {
    float* pr = part + ((size_t)(b * NH + h) * NCHUNK + cc) * NL + l0;
    if (l0 + 3 < LP) {
      *(v4f*)pr = *(v4f*)acc[h];
    } else {
#pragma unroll
      for (int j = 0; j < 4; ++j)
        if (l0 + j < LP) pr[j] = acc[h][j];
    }
  }
}

// Kernel 2 (R8-proven, verbatim): one 256-thread block per (b,h). Sum 8
// partials (+bias) into LDS, BN stats, exact radix-select of the k-th
// largest (stable ties like lax.top_k), sigmoid mask, 3-tap box sum, write
// cw*M into the xi row.
__global__ __launch_bounds__(256) void select_block(
    const float* __restrict__ part, float* __restrict__ xi,
    const float* __restrict__ conv_b, const float* __restrict__ bn_gamma,
    const float* __restrict__ bn_beta, const float* __restrict__ comb_w,
    const int* __restrict__ kptr) {
  const int t = threadIdx.x;
  const int lane = t & 63, wid = t >> 6;
  const int bh = blockIdx.x;
  const int h = bh & (NH - 1);
  __shared__ float xs[LP];
  __shared__ float smp[NL + 2];  // m shifted by 2, zero-padded both ends
  __shared__ int hist[256];
  __shared__ float rs[8];
  __shared__ float fbc[2];
  __shared__ int irs[8];
  __shared__ int ibc[4];

  const float cb = conv_b[h];
  const float* p0 = part + (size_t)bh * NCHUNK * NL;
  float s1 = 0.f, s2 = 0.f;
  for (int i = t; i < LP; i += 256) {
    float v0 = p0[i]           + p0[i + NL];
    float v1 = p0[i + 2 * NL]  + p0[i + 3 * NL];
    float v2 = p0[i + 4 * NL]  + p0[i + 5 * NL];
    float v3 = p0[i + 6 * NL]  + p0[i + 7 * NL];
    float v = ((v0 + v1) + (v2 + v3)) + cb;
    xs[i] = v;
    s1 += v;
    s2 += v * v;
  }
#pragma unroll
  for (int off = 32; off > 0; off >>= 1) {
    s1 += __shfl_down(s1, off);
    s2 += __shfl_down(s2, off);
  }
  if (lane == 0) { rs[wid] = s1; rs[wid + 4] = s2; }
  __syncthreads();
  if (t == 0) {
    float S = rs[0] + rs[1] + rs[2] + rs[3];
    float Q = rs[4] + rs[5] + rs[6] + rs[7];
    float mu = S / (float)LP;
    float var = Q / (float)LP - mu * mu;
    float inv = rsqrtf(var + 1e-5f);
    float sc = bn_gamma[h] * inv;
    fbc[0] = sc;
    fbc[1] = bn_beta[h] - mu * sc;
  }
  __syncthreads();
  {
    const float sc = fbc[0], sh = fbc[1];
    for (int i = t; i < LP; i += 256) xs[i] = fmaf(xs[i], sc, sh);
  }
  // exact radix select of the k-th largest key (4x 8-bit passes)
  int kk = kptr[0];
  const int ktot = kk;
  unsigned prefix = 0, pm = 0;
  for (int pass = 0; pass < 4; ++pass) {
    const int shift = 24 - 8 * pass;
    hist[t] = 0;
    __syncthreads();
    for (int i = t; i < LP; i += 256) {
      unsigned u = fkey(xs[i]);
      if ((u & pm) == prefix) atomicAdd(&hist[(u >> shift) & 255], 1);
    }
    __syncthreads();
    if (t < 64) {  // wave 0: suffix-scan 256 bins, 4 bins/lane
      const int h0 = hist[t * 4 + 0], h1 = hist[t * 4 + 1];
      const int h2 = hist[t * 4 + 2], h3 = hist[t * 4 + 3];
      const int g = h0 + h1 + h2 + h3;
      int sfx = g;
#pragma unroll
      for (int off = 1; off < 64; off <<= 1) {
        int o = __shfl(sfx, (t + off) & 63);
        if (t + off < 64) sfx += o;
      }
      const int A = sfx - g;  // strictly-higher groups
      const int s3 = A + h3, s2i = s3 + h2, s1i = s2i + h1, s0i = s1i + h0;
      int mybin = -1, mykk = 0;
      if (s0i >= kk && s0i - h0 < kk) { mybin = t * 4 + 0; mykk = kk - (s0i - h0); }
      if (s1i >= kk && s1i - h1 < kk) { mybin = t * 4 + 1; mykk = kk - (s1i - h1); }
      if (s2i >= kk && s2i - h2 < kk) { mybin = t * 4 + 2; mykk = kk - (s2i - h2); }
      if (s3  >= kk && s3  - h3 < kk) { mybin = t * 4 + 3; mykk = kk - (s3 - h3); }
      if (mybin >= 0) { ibc[0] = mybin; ibc[1] = mykk; }  // unique crossing
    }
    __syncthreads();
    prefix |= ((unsigned)ibc[0]) << shift;
    pm |= 255u << shift;
    kk = ibc[1];
  }
  const unsigned T = prefix;

  // counts for tie handling
  int cgt = 0, ceq = 0;
  for (int i = t; i < LP; i += 256) {
    unsigned u = fkey(xs[i]);
    cgt += (u > T);
    ceq += (u == T);
  }
#pragma unroll
  for (int off = 32; off > 0; off >>= 1) {
    cgt += __shfl_down(cgt, off);
    ceq += __shfl_down(ceq, off);
  }
  if (lane == 0) { irs[wid] = cgt; irs[wid + 4] = ceq; }
  __syncthreads();
  if (t == 0) {
    ibc[2] = irs[0] + irs[1] + irs[2] + irs[3];
    ibc[3] = irs[4] + irs[5] + irs[6] + irs[7];
  }
  __syncthreads();
  const int need_eq = ktot - ibc[2];
  const bool tie = (ibc[3] != need_eq);

  // mask + sigmoid -> smp (shifted by 2)
  for (int i = t; i < LP; i += 256) {
    float x = xs[i];
    unsigned u = fkey(x);
    bool sel = tie ? (u > T) : (u >= T);
    smp[i + 2] = sel ? 1.f / (1.f + __expf(-x)) : 0.f;
  }
  if (t < 2) { smp[t] = 0.f; smp[NL + t] = 0.f; }
  __syncthreads();
  if (tie && t == 0) {  // rare: stable lowest-index-first like lax.top_k
    int taken = 0;
    for (int i = 0; i < LP && taken < need_eq; ++i) {
      float x = xs[i];
      if (fkey(x) == T) { smp[i + 2] = 1.f / (1.f + __expf(-x)); ++taken; }
    }
  }
  __syncthreads();

  // 3-tap box sum; write this head's gate contribution
  const float cw = comb_w[h] * (1.0f / (float)KW);
  float* row = xi + (size_t)bh * NL;
  for (int l = t; l < NL; l += 256)
    row[l] = cw * ((smp[l + 2] + smp[l + 1]) + smp[l]);
}

// Kernel 3 (R8-proven, verbatim): each thread owns one (b,l4) pair,
// computes the 8-head gate sum ONCE, reuses it across 16 channels of
// coalesced src-load + NT-store.
__global__ __launch_bounds__(256) void scale_gate(
    const float* __restrict__ src, const float* __restrict__ xi,
    const float* __restrict__ comb_b, float* __restrict__ out) {
  const int t = threadIdx.x;
  const int cchunk = blockIdx.x >> 7;               // 0..15, 16 channels each
  const int pairidx = (blockIdx.x & 127) * 256 + t; // 0..32767
  const int b = pairidx >> 9;                       // NL/4 = 512 l4 per b
  const int l4 = pairidx & 511;
  const float cb = comb_b[0];

  const v4f* xp = (const v4f*)(xi + (size_t)b * NH * NL) + l4;
  v4f g = xp[0];
#pragma unroll
  for (int h = 1; h < NH; ++h) g += xp[(size_t)h * (NL / 4)];

  const int c0 = cchunk * (NC / 16);
  const v4f* sp = (const v4f*)src + ((size_t)b * NC + c0) * (NL / 4) + l4;
  v4f* op = (v4f*)out + ((size_t)b * NC + c0) * (NL / 4) + l4;
#pragma unroll 4
  for (int c = 0; c < NC / 16; ++c) {
    v4f sv = sp[(size_t)c * (NL / 4)];
    v4f ov;
    ov.x = fmaf(sv.x, g.x, cb);
    ov.y = fmaf(sv.y, g.y, cb);
    ov.z = fmaf(sv.z, g.z, cb);
    ov.w = fmaf(sv.w, g.w, cb);
    __builtin_nontemporal_store(ov, op + (size_t)c * (NL / 4));
  }
}

extern "C" void kernel_launch(void* const* d_in, const int* in_sizes, int n_in,
                              void* d_out, int out_size, void* d_ws, size_t ws_size,
                              hipStream_t stream) {
  const float* src = (const float*)d_in[0];
  const float* conv_w = (const float*)d_in[1];
  const float* conv_b = (const float*)d_in[2];
  const float* bn_gamma = (const float*)d_in[3];
  const float* bn_beta = (const float*)d_in[4];
  const float* comb_w = (const float*)d_in[5];
  const float* comb_b = (const float*)d_in[6];
  const int* kptr = (const int*)d_in[7];
  float* out = (float*)d_out;

  float* xi = (float*)d_ws;  // NB*NH*NL floats (4 MB)
  float* part = out;         // 32 MB scratch inside d_out: consumed by
                             // select_block, then overwritten by scale_gate

  // DIAGNOSTIC: conv launched twice (identical output; deterministic).
  // total_dur - 92.7us (R8 baseline) = conv's true duration.
  conv_partial<<<dim3(2, NB, NCHUNK), 256, 0, stream>>>(src, conv_w, part);
  conv_partial<<<dim3(2, NB, NCHUNK), 256, 0, stream>>>(src, conv_w, part);
  select_block<<<NB * NH, 256, 0, stream>>>(part, xi, conv_b, bn_gamma,
                                            bn_beta, comb_w, kptr);
  scale_gate<<<2048, 256, 0, stream>>>(src, xi, comb_b, out);
}

// Round 16
// 91.421 us; speedup vs baseline: 1.3096x; 1.3096x over previous
//
#include <hip/hip_runtime.h>
#include <hip/hip_bf16.h>

#define NB 64
#define NC 256
#define NL 2048
#define NH 8
#define KW 3
#define LP (NL - KW + 1)  // 2046
#define NCHUNK 8
#define CPC (NC / NCHUNK)  // 32 channels per chunk

typedef float v4f __attribute__((ext_vector_type(4)));

// monotonic float->uint key: order(u) == order(x)
__device__ __forceinline__ unsigned fkey(float x) {
  unsigned b = __float_as_uint(x);
  return (b & 0x80000000u) ? ~b : (b | 0x80000000u);
}

// Kernel 1 (R8-proven, verbatim): conv1d partial sums. ~27us steady-state
// (measured R15 via double-launch), near its 134MB+32MB traffic floor.
__global__ __launch_bounds__(256) void conv_partial(
    const float* __restrict__ src, const float* __restrict__ conv_w,
    float* __restrict__ part) {
  const int t = threadIdx.x;
  const int lane = t & 63;
  const int l0 = blockIdx.x * 1024 + t * 4;
  const int b = blockIdx.y;
  const int cc = blockIdx.z;
  const int c0 = cc * CPC;

  float acc[NH][4];
#pragma unroll
  for (int h = 0; h < NH; ++h)
#pragma unroll
    for (int j = 0; j < 4; ++j) acc[h][j] = 0.f;

  const float* sp = src + ((size_t)b * NC + c0) * NL + l0;
  const bool tail = (lane == 63) && (l0 + 5 < NL);
#pragma unroll 2
  for (int c = 0; c < CPC; ++c) {
    v4f v = *(const v4f*)sp;
    float e0 = 0.f, e1 = 0.f;
    if (tail) { e0 = sp[4]; e1 = sp[5]; }
    sp += NL;
    float n0 = __shfl_down(v.x, 1);
    float n1 = __shfl_down(v.y, 1);
    if (lane == 63) { n0 = e0; n1 = e1; }
    float s0 = v.x, s1 = v.y, s2 = v.z, s3 = v.w, s4 = n0, s5 = n1;
#pragma unroll
    for (int h = 0; h < NH; ++h) {
      const float* w = conv_w + (h * NC + c0 + c) * KW;  // uniform -> s_load
      const float w0 = w[0], w1 = w[1], w2 = w[2];
      acc[h][0] = fmaf(s0, w0, fmaf(s1, w1, fmaf(s2, w2, acc[h][0])));
      acc[h][1] = fmaf(s1, w0, fmaf(s2, w1, fmaf(s3, w2, acc[h][1])));
      acc[h][2] = fmaf(s2, w0, fmaf(s3, w1, fmaf(s4, w2, acc[h][2])));
      acc[h][3] = fmaf(s3, w0, fmaf(s4, w1, fmaf(s5, w2, acc[h][3])));
    }
  }
#pragma unroll
  for (int h = 0; h < NH; ++h) {
    float* pr = part + ((size_t)(b * NH + h) * NCHUNK + cc) * NL + l0;
    if (l0 + 3 < LP) {
      *(v4f*)pr = *(v4f*)acc[h];
    } else {
#pragma unroll
      for (int j = 0; j < 4; ++j)
        if (l0 + j < LP) pr[j] = acc[h][j];
    }
  }
}

// Kernel 2 (LEANED R16): one 256-thread block per (b,h).
// vs R8: (1) BN-normalize fused into radix pass 0 (-1 sweep);
// (2) pass-0 candidate bin compacted into a small LDS list, passes 1-3
//     sweep only the list (-3 full sweeps); cand[] aliases smp[] (fully
//     overwritten by the mask phase afterwards);
// (3) tie counts derived from radix state (need_eq = final kk,
//     ceq = final-pass bin count) — the extra count sweep is deleted.
__global__ __launch_bounds__(256) void select_block(
    const float* __restrict__ part, float* __restrict__ xi,
    const float* __restrict__ conv_b, const float* __restrict__ bn_gamma,
    const float* __restrict__ bn_beta, const float* __restrict__ comb_w,
    const int* __restrict__ kptr) {
  const int t = threadIdx.x;
  const int lane = t & 63, wid = t >> 6;
  const int bh = blockIdx.x;
  const int h = bh & (NH - 1);
  __shared__ float xs[LP];
  __shared__ float smp[NL + 4];  // doubles as cand[] during radix passes
  __shared__ int hist[256];
  __shared__ float rs[8];
  __shared__ float fbc[2];
  __shared__ int ibc[4];  // [0]=bin [1]=kk-next [3]=selected-bin count
  __shared__ int cnt;
  float* cand = smp;

  // phase A: sum 8 partials (+bias) into xs, raw stats
  const float cb = conv_b[h];
  const float* p0 = part + (size_t)bh * NCHUNK * NL;
  float s1 = 0.f, s2 = 0.f;
  for (int i = t; i < LP; i += 256) {
    float v0 = p0[i]           + p0[i + NL];
    float v1 = p0[i + 2 * NL]  + p0[i + 3 * NL];
    float v2 = p0[i + 4 * NL]  + p0[i + 5 * NL];
    float v3 = p0[i + 6 * NL]  + p0[i + 7 * NL];
    float v = ((v0 + v1) + (v2 + v3)) + cb;
    xs[i] = v;
    s1 += v;
    s2 += v * v;
  }
  hist[t] = 0;  // pre-zero pass-0 histogram (used two barriers later)
#pragma unroll
  for (int off = 32; off > 0; off >>= 1) {
    s1 += __shfl_down(s1, off);
    s2 += __shfl_down(s2, off);
  }
  if (lane == 0) { rs[wid] = s1; rs[wid + 4] = s2; }
  __syncthreads();
  if (t == 0) {
    float S = rs[0] + rs[1] + rs[2] + rs[3];
    float Q = rs[4] + rs[5] + rs[6] + rs[7];
    float mu = S / (float)LP;
    float var = Q / (float)LP - mu * mu;
    float inv = rsqrtf(var + 1e-5f);
    float sc = bn_gamma[h] * inv;
    fbc[0] = sc;
    fbc[1] = bn_beta[h] - mu * sc;
    cnt = 0;
  }
  __syncthreads();

  // pass 0: normalize (in place, own indices) + top-byte histogram
  {
    const float sc = fbc[0], sh = fbc[1];
    for (int i = t; i < LP; i += 256) {
      float v = fmaf(xs[i], sc, sh);
      xs[i] = v;
      atomicAdd(&hist[fkey(v) >> 24], 1);
    }
  }
  __syncthreads();

  int kk = kptr[0];
  // wave-0 suffix-scan over 256 bins, 4 bins/lane: find crossing bin
#define RADIX_SCAN()                                                          \
  if (t < 64) {                                                               \
    const int h0 = hist[t * 4 + 0], h1 = hist[t * 4 + 1];                     \
    const int h2 = hist[t * 4 + 2], h3 = hist[t * 4 + 3];                     \
    const int g = h0 + h1 + h2 + h3;                                          \
    int sfx = g;                                                              \
    _Pragma("unroll")                                                         \
    for (int off = 1; off < 64; off <<= 1) {                                  \
      int o = __shfl(sfx, (t + off) & 63);                                    \
      if (t + off < 64) sfx += o;                                             \
    }                                                                         \
    const int A = sfx - g;                                                    \
    const int q3 = A + h3, q2 = q3 + h2, q1 = q2 + h1, q0 = q1 + h0;          \
    int mybin = -1, mykk = 0, myct = 0;                                       \
    if (q0 >= kk && q0 - h0 < kk) { mybin = t * 4 + 0; mykk = kk - (q0 - h0); myct = h0; } \
    if (q1 >= kk && q1 - h1 < kk) { mybin = t * 4 + 1; mykk = kk - (q1 - h1); myct = h1; } \
    if (q2 >= kk && q2 - h2 < kk) { mybin = t * 4 + 2; mykk = kk - (q2 - h2); myct = h2; } \
    if (q3 >= kk && q3 - h3 < kk) { mybin = t * 4 + 3; mykk = kk - (q3 - h3); myct = h3; } \
    if (mybin >= 0) { ibc[0] = mybin; ibc[1] = mykk; ibc[3] = myct; }         \
  }

  RADIX_SCAN();
  __syncthreads();
  unsigned prefix = ((unsigned)ibc[0]) << 24;
  unsigned pm = 0xFF000000u;
  kk = ibc[1];
  const unsigned b0 = (unsigned)ibc[0];

  // compact the selected top-byte bin into cand[] (order-independent result)
  for (int i = t; i < LP; i += 256) {
    float x = xs[i];
    if ((fkey(x) >> 24) == b0) {
      int p = atomicAdd(&cnt, 1);
      cand[p] = x;
    }
  }
  __syncthreads();
  const int n1 = cnt;

  // passes 1..3 over the small candidate list
  for (int pass = 1; pass < 4; ++pass) {
    const int shift = 24 - 8 * pass;
    hist[t] = 0;
    __syncthreads();
    for (int i = t; i < n1; i += 256) {
      unsigned u = fkey(cand[i]);
      if ((u & pm) == prefix) atomicAdd(&hist[(u >> shift) & 255], 1);
    }
    __syncthreads();
    RADIX_SCAN();
    __syncthreads();
    prefix |= ((unsigned)ibc[0]) << shift;
    pm |= 255u << shift;
    kk = ibc[1];
  }
  const unsigned T = prefix;
  const int need_eq = kk;      // # needed among keys == T (derived)
  const int ceq = ibc[3];      // # keys == T (final-pass bin count)
  const bool tie = (ceq != need_eq);

  // mask + sigmoid -> smp (fully overwrites the cand alias)
  for (int i = t; i < LP; i += 256) {
    float x = xs[i];
    unsigned u = fkey(x);
    bool sel = tie ? (u > T) : (u >= T);
    smp[i + 2] = sel ? 1.f / (1.f + __expf(-x)) : 0.f;
  }
  if (t < 2) { smp[t] = 0.f; smp[NL + t] = 0.f; }
  __syncthreads();
  if (tie && t == 0) {  // rare: stable lowest-index-first like lax.top_k
    int taken = 0;
    for (int i = 0; i < LP && taken < need_eq; ++i) {
      float x = xs[i];
      if (fkey(x) == T) { smp[i + 2] = 1.f / (1.f + __expf(-x)); ++taken; }
    }
  }
  __syncthreads();

  // 3-tap box sum; write this head's gate contribution
  const float cw = comb_w[h] * (1.0f / (float)KW);
  float* row = xi + (size_t)bh * NL;
  for (int l = t; l < NL; l += 256)
    row[l] = cw * ((smp[l + 2] + smp[l + 1]) + smp[l]);
}

// Kernel 3 (R8-proven, verbatim): each thread owns one (b,l4) pair,
// computes the 8-head gate sum ONCE, reuses it across 16 channels of
// coalesced src-load + NT-store. ~38-40us, at the measured fill-rate
// ceiling for its 268MB of traffic.
__global__ __launch_bounds__(256) void scale_gate(
    const float* __restrict__ src, const float* __restrict__ xi,
    const float* __restrict__ comb_b, float* __restrict__ out) {
  const int t = threadIdx.x;
  const int cchunk = blockIdx.x >> 7;               // 0..15, 16 channels each
  const int pairidx = (blockIdx.x & 127) * 256 + t; // 0..32767
  const int b = pairidx >> 9;                       // NL/4 = 512 l4 per b
  const int l4 = pairidx & 511;
  const float cb = comb_b[0];

  const v4f* xp = (const v4f*)(xi + (size_t)b * NH * NL) + l4;
  v4f g = xp[0];
#pragma unroll
  for (int h = 1; h < NH; ++h) g += xp[(size_t)h * (NL / 4)];

  const int c0 = cchunk * (NC / 16);
  const v4f* sp = (const v4f*)src + ((size_t)b * NC + c0) * (NL / 4) + l4;
  v4f* op = (v4f*)out + ((size_t)b * NC + c0) * (NL / 4) + l4;
#pragma unroll 4
  for (int c = 0; c < NC / 16; ++c) {
    v4f sv = sp[(size_t)c * (NL / 4)];
    v4f ov;
    ov.x = fmaf(sv.x, g.x, cb);
    ov.y = fmaf(sv.y, g.y, cb);
    ov.z = fmaf(sv.z, g.z, cb);
    ov.w = fmaf(sv.w, g.w, cb);
    __builtin_nontemporal_store(ov, op + (size_t)c * (NL / 4));
  }
}

extern "C" void kernel_launch(void* const* d_in, const int* in_sizes, int n_in,
                              void* d_out, int out_size, void* d_ws, size_t ws_size,
                              hipStream_t stream) {
  const float* src = (const float*)d_in[0];
  const float* conv_w = (const float*)d_in[1];
  const float* conv_b = (const float*)d_in[2];
  const float* bn_gamma = (const float*)d_in[3];
  const float* bn_beta = (const float*)d_in[4];
  const float* comb_w = (const float*)d_in[5];
  const float* comb_b = (const float*)d_in[6];
  const int* kptr = (const int*)d_in[7];
  float* out = (float*)d_out;

  float* xi = (float*)d_ws;  // NB*NH*NL floats (4 MB)
  float* part = out;         // 32 MB scratch inside d_out: consumed by
                             // select_block, then overwritten by scale_gate

  conv_partial<<<dim3(2, NB, NCHUNK), 256, 0, stream>>>(src, conv_w, part);
  select_block<<<NB * NH, 256, 0, stream>>>(part, xi, conv_b, bn_gamma,
                                            bn_beta, comb_w, kptr);
  scale_gate<<<2048, 256, 0, stream>>>(src, xi, comb_b, out);
}

// Round 17
// 90.022 us; speedup vs baseline: 1.3299x; 1.0155x over previous
//
#include <hip/hip_runtime.h>
#include <hip/hip_bf16.h>

#define NB 64
#define NC 256
#define NL 2048
#define NH 8
#define KW 3
#define LP (NL - KW + 1)  // 2046
#define NCHUNK 8
#define CPC (NC / NCHUNK)  // 32 channels per chunk

typedef float v4f __attribute__((ext_vector_type(4)));

// monotonic float->uint key: order(u) == order(x)
__device__ __forceinline__ unsigned fkey(float x) {
  unsigned b = __float_as_uint(x);
  return (b & 0x80000000u) ? ~b : (b | 0x80000000u);
}

// Kernel 1 (R8-proven, verbatim): conv1d partial sums. ~27us steady-state
// (measured R15 via double-launch), near its 134MB+32MB traffic floor.
__global__ __launch_bounds__(256) void conv_partial(
    const float* __restrict__ src, const float* __restrict__ conv_w,
    float* __restrict__ part) {
  const int t = threadIdx.x;
  const int lane = t & 63;
  const int l0 = blockIdx.x * 1024 + t * 4;
  const int b = blockIdx.y;
  const int cc = blockIdx.z;
  const int c0 = cc * CPC;

  float acc[NH][4];
#pragma unroll
  for (int h = 0; h < NH; ++h)
#pragma unroll
    for (int j = 0; j < 4; ++j) acc[h][j] = 0.f;

  const float* sp = src + ((size_t)b * NC + c0) * NL + l0;
  const bool tail = (lane == 63) && (l0 + 5 < NL);
#pragma unroll 2
  for (int c = 0; c < CPC; ++c) {
    v4f v = *(const v4f*)sp;
    float e0 = 0.f, e1 = 0.f;
    if (tail) { e0 = sp[4]; e1 = sp[5]; }
    sp += NL;
    float n0 = __shfl_down(v.x, 1);
    float n1 = __shfl_down(v.y, 1);
    if (lane == 63) { n0 = e0; n1 = e1; }
    float s0 = v.x, s1 = v.y, s2 = v.z, s3 = v.w, s4 = n0, s5 = n1;
#pragma unroll
    for (int h = 0; h < NH; ++h) {
      const float* w = conv_w + (h * NC + c0 + c) * KW;  // uniform -> s_load
      const float w0 = w[0], w1 = w[1], w2 = w[2];
      acc[h][0] = fmaf(s0, w0, fmaf(s1, w1, fmaf(s2, w2, acc[h][0])));
      acc[h][1] = fmaf(s1, w0, fmaf(s2, w1, fmaf(s3, w2, acc[h][1])));
      acc[h][2] = fmaf(s2, w0, fmaf(s3, w1, fmaf(s4, w2, acc[h][2])));
      acc[h][3] = fmaf(s3, w0, fmaf(s4, w1, fmaf(s5, w2, acc[h][3])));
    }
  }
#pragma unroll
  for (int h = 0; h < NH; ++h) {
    float* pr = part + ((size_t)(b * NH + h) * NCHUNK + cc) * NL + l0;
    if (l0 + 3 < LP) {
      *(v4f*)pr = *(v4f*)acc[h];
    } else {
#pragma unroll
      for (int j = 0; j < 4; ++j)
        if (l0 + j < LP) pr[j] = acc[h][j];
    }
  }
}

// Kernel 2 (R16 machinery + v4f phase A + v4f box-sum write).
__global__ __launch_bounds__(256) void select_block(
    const float* __restrict__ part, float* __restrict__ xi,
    const float* __restrict__ conv_b, const float* __restrict__ bn_gamma,
    const float* __restrict__ bn_beta, const float* __restrict__ comb_w,
    const int* __restrict__ kptr) {
  const int t = threadIdx.x;
  const int lane = t & 63, wid = t >> 6;
  const int bh = blockIdx.x;
  const int h = bh & (NH - 1);
  __shared__ __align__(16) float xs[NL];       // padded to 2048 (tail unused)
  __shared__ __align__(16) float smp[NL + 4];  // doubles as cand[] in radix
  __shared__ int hist[256];
  __shared__ float rs[8];
  __shared__ float fbc[2];
  __shared__ int ibc[4];
  __shared__ int cnt;
  float* cand = smp;

  // phase A: v4f-vectorized sum of 8 partial streams (+bias), raw stats.
  // 16 v4f loads/thread (was 64 scalar) — part is L2/L3-resident.
  const float cb = conv_b[h];
  const float* p0 = part + (size_t)bh * NCHUNK * NL;
  const v4f* p0v = (const v4f*)p0;
  const v4f cbv = {cb, cb, cb, cb};
  float s1 = 0.f, s2 = 0.f;
#pragma unroll
  for (int half = 0; half < 2; ++half) {
    const int i0 = half * 1024 + t * 4;  // 0..2044, %4==0
    const int j = i0 >> 2;
    v4f a0 = p0v[j]        + p0v[j + 512];
    v4f a1 = p0v[j + 1024] + p0v[j + 1536];
    v4f a2 = p0v[j + 2048] + p0v[j + 2560];
    v4f a3 = p0v[j + 3072] + p0v[j + 3584];
    v4f v = ((a0 + a1) + (a2 + a3)) + cbv;
    *(v4f*)&xs[i0] = v;
    if (i0 + 3 < LP) {
      s1 += (v.x + v.y) + (v.z + v.w);
      s2 += (v.x * v.x + v.y * v.y) + (v.z * v.z + v.w * v.w);
    } else {  // i0 == 2044: only elements 2044,2045 are real
      s1 += v.x + v.y;
      s2 += v.x * v.x + v.y * v.y;
    }
  }
  hist[t] = 0;  // pre-zero pass-0 histogram
#pragma unroll
  for (int off = 32; off > 0; off >>= 1) {
    s1 += __shfl_down(s1, off);
    s2 += __shfl_down(s2, off);
  }
  if (lane == 0) { rs[wid] = s1; rs[wid + 4] = s2; }
  __syncthreads();
  if (t == 0) {
    float S = rs[0] + rs[1] + rs[2] + rs[3];
    float Q = rs[4] + rs[5] + rs[6] + rs[7];
    float mu = S / (float)LP;
    float var = Q / (float)LP - mu * mu;
    float inv = rsqrtf(var + 1e-5f);
    float sc = bn_gamma[h] * inv;
    fbc[0] = sc;
    fbc[1] = bn_beta[h] - mu * sc;
    cnt = 0;
  }
  __syncthreads();

  // pass 0: normalize (in place) + top-byte histogram
  {
    const float sc = fbc[0], sh = fbc[1];
    for (int i = t; i < LP; i += 256) {
      float v = fmaf(xs[i], sc, sh);
      xs[i] = v;
      atomicAdd(&hist[fkey(v) >> 24], 1);
    }
  }
  __syncthreads();

  int kk = kptr[0];
#define RADIX_SCAN()                                                          \
  if (t < 64) {                                                               \
    const int h0 = hist[t * 4 + 0], h1 = hist[t * 4 + 1];                     \
    const int h2 = hist[t * 4 + 2], h3 = hist[t * 4 + 3];                     \
    const int g = h0 + h1 + h2 + h3;                                          \
    int sfx = g;                                                              \
    _Pragma("unroll")                                                         \
    for (int off = 1; off < 64; off <<= 1) {                                  \
      int o = __shfl(sfx, (t + off) & 63);                                    \
      if (t + off < 64) sfx += o;                                             \
    }                                                                         \
    const int A = sfx - g;                                                    \
    const int q3 = A + h3, q2 = q3 + h2, q1 = q2 + h1, q0 = q1 + h0;          \
    int mybin = -1, mykk = 0, myct = 0;                                       \
    if (q0 >= kk && q0 - h0 < kk) { mybin = t * 4 + 0; mykk = kk - (q0 - h0); myct = h0; } \
    if (q1 >= kk && q1 - h1 < kk) { mybin = t * 4 + 1; mykk = kk - (q1 - h1); myct = h1; } \
    if (q2 >= kk && q2 - h2 < kk) { mybin = t * 4 + 2; mykk = kk - (q2 - h2); myct = h2; } \
    if (q3 >= kk && q3 - h3 < kk) { mybin = t * 4 + 3; mykk = kk - (q3 - h3); myct = h3; } \
    if (mybin >= 0) { ibc[0] = mybin; ibc[1] = mykk; ibc[3] = myct; }         \
  }

  RADIX_SCAN();
  __syncthreads();
  unsigned prefix = ((unsigned)ibc[0]) << 24;
  unsigned pm = 0xFF000000u;
  kk = ibc[1];
  const unsigned b0 = (unsigned)ibc[0];

  // compact the selected top-byte bin into cand[]
  for (int i = t; i < LP; i += 256) {
    float x = xs[i];
    if ((fkey(x) >> 24) == b0) {
      int p = atomicAdd(&cnt, 1);
      cand[p] = x;
    }
  }
  __syncthreads();
  const int n1 = cnt;

  // passes 1..3 over the small candidate list
  for (int pass = 1; pass < 4; ++pass) {
    const int shift = 24 - 8 * pass;
    hist[t] = 0;
    __syncthreads();
    for (int i = t; i < n1; i += 256) {
      unsigned u = fkey(cand[i]);
      if ((u & pm) == prefix) atomicAdd(&hist[(u >> shift) & 255], 1);
    }
    __syncthreads();
    RADIX_SCAN();
    __syncthreads();
    prefix |= ((unsigned)ibc[0]) << shift;
    pm |= 255u << shift;
    kk = ibc[1];
  }
  const unsigned T = prefix;
  const int need_eq = kk;
  const int ceq = ibc[3];
  const bool tie = (ceq != need_eq);

  // mask + sigmoid -> smp (fully overwrites the cand alias)
  for (int i = t; i < LP; i += 256) {
    float x = xs[i];
    unsigned u = fkey(x);
    bool sel = tie ? (u > T) : (u >= T);
    smp[i + 2] = sel ? 1.f / (1.f + __expf(-x)) : 0.f;
  }
  if (t < 2) smp[t] = 0.f;
  if (t < 4) smp[NL + t] = 0.f;   // covers smp[2048..2051] for v4f reads
  __syncthreads();
  if (tie && t == 0) {  // rare: stable lowest-index-first like lax.top_k
    int taken = 0;
    for (int i = 0; i < LP && taken < need_eq; ++i) {
      float x = xs[i];
      if (fkey(x) == T) { smp[i + 2] = 1.f / (1.f + __expf(-x)); ++taken; }
    }
  }
  __syncthreads();

  // 3-tap box sum, v4f output (in-register shifts from two aligned LDS v4f)
  const float cw = comb_w[h] * (1.0f / (float)KW);
  float* row = xi + (size_t)bh * NL;
#pragma unroll
  for (int q = 0; q < 2; ++q) {
    const int l = q * 1024 + t * 4;
    v4f a = *(const v4f*)&smp[l];
    v4f bsh = *(const v4f*)&smp[l + 4];
    v4f u1 = {a.y, a.z, a.w, bsh.x};
    v4f u2 = {a.z, a.w, bsh.x, bsh.y};
    v4f r = (a + u1 + u2);
    r.x *= cw; r.y *= cw; r.z *= cw; r.w *= cw;
    *(v4f*)&row[l] = r;
  }
}

// Kernel 3 (R8 structure, NT store REMOVED): each thread owns one (b,l4)
// pair, computes the 8-head gate sum once, reuses it across 16 channels.
// Plain stores let the 134MB out-write be absorbed by the write-back L2/L3
// instead of (possibly) streaming synchronously to HBM.
__global__ __launch_bounds__(256) void scale_gate(
    const float* __restrict__ src, const float* __restrict__ xi,
    const float* __restrict__ comb_b, float* __restrict__ out) {
  const int t = threadIdx.x;
  const int cchunk = blockIdx.x >> 7;               // 0..15, 16 channels each
  const int pairidx = (blockIdx.x & 127) * 256 + t; // 0..32767
  const int b = pairidx >> 9;                       // NL/4 = 512 l4 per b
  const int l4 = pairidx & 511;
  const float cb = comb_b[0];

  const v4f* xp = (const v4f*)(xi + (size_t)b * NH * NL) + l4;
  v4f g = xp[0];
#pragma unroll
  for (int h = 1; h < NH; ++h) g += xp[(size_t)h * (NL / 4)];

  const int c0 = cchunk * (NC / 16);
  const v4f* sp = (const v4f*)src + ((size_t)b * NC + c0) * (NL / 4) + l4;
  v4f* op = (v4f*)out + ((size_t)b * NC + c0) * (NL / 4) + l4;
#pragma unroll 4
  for (int c = 0; c < NC / 16; ++c) {
    v4f sv = sp[(size_t)c * (NL / 4)];
    v4f ov;
    ov.x = fmaf(sv.x, g.x, cb);
    ov.y = fmaf(sv.y, g.y, cb);
    ov.z = fmaf(sv.z, g.z, cb);
    ov.w = fmaf(sv.w, g.w, cb);
    op[(size_t)c * (NL / 4)] = ov;
  }
}

extern "C" void kernel_launch(void* const* d_in, const int* in_sizes, int n_in,
                              void* d_out, int out_size, void* d_ws, size_t ws_size,
                              hipStream_t stream) {
  const float* src = (const float*)d_in[0];
  const float* conv_w = (const float*)d_in[1];
  const float* conv_b = (const float*)d_in[2];
  const float* bn_gamma = (const float*)d_in[3];
  const float* bn_beta = (const float*)d_in[4];
  const float* comb_w = (const float*)d_in[5];
  const float* comb_b = (const float*)d_in[6];
  const int* kptr = (const int*)d_in[7];
  float* out = (float*)d_out;

  float* xi = (float*)d_ws;  // NB*NH*NL floats (4 MB)
  float* part = out;         // 32 MB scratch inside d_out: consumed by
                             // select_block, then overwritten by scale_gate

  conv_partial<<<dim3(2, NB, NCHUNK), 256, 0, stream>>>(src, conv_w, part);
  select_block<<<NB * NH, 256, 0, stream>>>(part, xi, conv_b, bn_gamma,
                                            bn_beta, comb_w, kptr);
  scale_gate<<<2048, 256, 0, stream>>>(src, xi, comb_b, out);
}

// Round 18
// 89.467 us; speedup vs baseline: 1.3382x; 1.0062x over previous
//
#include <hip/hip_runtime.h>
#include <hip/hip_bf16.h>

#define NB 64
#define NC 256
#define NL 2048
#define NH 8
#define KW 3
#define LP (NL - KW + 1)  // 2046
#define NCHUNK 8
#define CPC (NC / NCHUNK)  // 32 channels per chunk

typedef float v4f __attribute__((ext_vector_type(4)));

// monotonic float->uint key: order(u) == order(x)
__device__ __forceinline__ unsigned fkey(float x) {
  unsigned b = __float_as_uint(x);
  return (b & 0x80000000u) ? ~b : (b | 0x80000000u);
}

// Kernel 1 (R8-proven, verbatim): conv1d partial sums. ~27us steady-state
// (measured R15 via double-launch), near its 134MB+32MB traffic floor.
__global__ __launch_bounds__(256) void conv_partial(
    const float* __restrict__ src, const float* __restrict__ conv_w,
    float* __restrict__ part) {
  const int t = threadIdx.x;
  const int lane = t & 63;
  const int l0 = blockIdx.x * 1024 + t * 4;
  const int b = blockIdx.y;
  const int cc = blockIdx.z;
  const int c0 = cc * CPC;

  float acc[NH][4];
#pragma unroll
  for (int h = 0; h < NH; ++h)
#pragma unroll
    for (int j = 0; j < 4; ++j) acc[h][j] = 0.f;

  const float* sp = src + ((size_t)b * NC + c0) * NL + l0;
  const bool tail = (lane == 63) && (l0 + 5 < NL);
#pragma unroll 2
  for (int c = 0; c < CPC; ++c) {
    v4f v = *(const v4f*)sp;
    float e0 = 0.f, e1 = 0.f;
    if (tail) { e0 = sp[4]; e1 = sp[5]; }
    sp += NL;
    float n0 = __shfl_down(v.x, 1);
    float n1 = __shfl_down(v.y, 1);
    if (lane == 63) { n0 = e0; n1 = e1; }
    float s0 = v.x, s1 = v.y, s2 = v.z, s3 = v.w, s4 = n0, s5 = n1;
#pragma unroll
    for (int h = 0; h < NH; ++h) {
      const float* w = conv_w + (h * NC + c0 + c) * KW;  // uniform -> s_load
      const float w0 = w[0], w1 = w[1], w2 = w[2];
      acc[h][0] = fmaf(s0, w0, fmaf(s1, w1, fmaf(s2, w2, acc[h][0])));
      acc[h][1] = fmaf(s1, w0, fmaf(s2, w1, fmaf(s3, w2, acc[h][1])));
      acc[h][2] = fmaf(s2, w0, fmaf(s3, w1, fmaf(s4, w2, acc[h][2])));
      acc[h][3] = fmaf(s3, w0, fmaf(s4, w1, fmaf(s5, w2, acc[h][3])));
    }
  }
#pragma unroll
  for (int h = 0; h < NH; ++h) {
    float* pr = part + ((size_t)(b * NH + h) * NCHUNK + cc) * NL + l0;
    if (l0 + 3 < LP) {
      *(v4f*)pr = *(v4f*)acc[h];
    } else {
#pragma unroll
      for (int j = 0; j < 4; ++j)
        if (l0 + j < LP) pr[j] = acc[h][j];
    }
  }
}

// Kernel 2 (R18: RAW-KEY radix — BN never materialized). BN is monotone
// affine (sign(sc)=sign(gamma), known at entry), so rank order in raw space
// equals rank order in normalized space (key-flipped if gamma<0). Phase A
// fuses load + stats + raw-key histogram into ONE sweep; pass 0's dedicated
// normalize+histogram sweep is deleted; BN applies only inside the sigmoid.
__global__ __launch_bounds__(256) void select_block(
    const float* __restrict__ part, float* __restrict__ xi,
    const float* __restrict__ conv_b, const float* __restrict__ bn_gamma,
    const float* __restrict__ bn_beta, const float* __restrict__ comb_w,
    const int* __restrict__ kptr) {
  const int t = threadIdx.x;
  const int lane = t & 63, wid = t >> 6;
  const int bh = blockIdx.x;
  const int h = bh & (NH - 1);
  __shared__ __align__(16) float xs[NL];       // raw values (pad tail unused)
  __shared__ __align__(16) float smp[NL + 4];  // doubles as cand[] in radix
  __shared__ int hist[256];
  __shared__ float rs[8];
  __shared__ float fbc[2];
  __shared__ int ibc[4];
  __shared__ int cnt;
  float* cand = smp;

  const float gma = bn_gamma[h];
  const unsigned kxor = (gma < 0.f) ? 0xFFFFFFFFu : 0u;  // key flip for sc<0
#define KEY(x) (fkey(x) ^ kxor)

  hist[t] = 0;
  __syncthreads();  // all histogram slots zeroed before any atomics

  // phase A: ONE sweep = v4f 8-stream sum (+bias) -> xs, raw stats,
  // raw-key top-byte histogram.
  const float cb = conv_b[h];
  const v4f* p0v = (const v4f*)(part + (size_t)bh * NCHUNK * NL);
  const v4f cbv = {cb, cb, cb, cb};
  float s1 = 0.f, s2 = 0.f;
#pragma unroll
  for (int half = 0; half < 2; ++half) {
    const int i0 = half * 1024 + t * 4;  // 0..2044, %4==0
    const int j = i0 >> 2;
    v4f a0 = p0v[j]        + p0v[j + 512];
    v4f a1 = p0v[j + 1024] + p0v[j + 1536];
    v4f a2 = p0v[j + 2048] + p0v[j + 2560];
    v4f a3 = p0v[j + 3072] + p0v[j + 3584];
    v4f v = ((a0 + a1) + (a2 + a3)) + cbv;
    *(v4f*)&xs[i0] = v;  // elements >= LP are never read by keyed sweeps
    if (i0 + 3 < LP) {
      s1 += (v.x + v.y) + (v.z + v.w);
      s2 += (v.x * v.x + v.y * v.y) + (v.z * v.z + v.w * v.w);
      atomicAdd(&hist[KEY(v.x) >> 24], 1);
      atomicAdd(&hist[KEY(v.y) >> 24], 1);
      atomicAdd(&hist[KEY(v.z) >> 24], 1);
      atomicAdd(&hist[KEY(v.w) >> 24], 1);
    } else {  // i0 == 2044: only 2044,2045 are real
      s1 += v.x + v.y;
      s2 += v.x * v.x + v.y * v.y;
      atomicAdd(&hist[KEY(v.x) >> 24], 1);
      atomicAdd(&hist[KEY(v.y) >> 24], 1);
    }
  }
#pragma unroll
  for (int off = 32; off > 0; off >>= 1) {
    s1 += __shfl_down(s1, off);
    s2 += __shfl_down(s2, off);
  }
  if (lane == 0) { rs[wid] = s1; rs[wid + 4] = s2; }
  __syncthreads();  // hist + rs complete

  int kk = kptr[0];
#define RADIX_SCAN()                                                          \
  if (t < 64) {                                                               \
    const int h0 = hist[t * 4 + 0], h1 = hist[t * 4 + 1];                     \
    const int h2 = hist[t * 4 + 2], h3 = hist[t * 4 + 3];                     \
    const int g = h0 + h1 + h2 + h3;                                          \
    int sfx = g;                                                              \
    _Pragma("unroll")                                                         \
    for (int off = 1; off < 64; off <<= 1) {                                  \
      int o = __shfl(sfx, (t + off) & 63);                                    \
      if (t + off < 64) sfx += o;                                             \
    }                                                                         \
    const int A = sfx - g;                                                    \
    const int q3 = A + h3, q2 = q3 + h2, q1 = q2 + h1, q0 = q1 + h0;          \
    int mybin = -1, mykk = 0, myct = 0;                                       \
    if (q0 >= kk && q0 - h0 < kk) { mybin = t * 4 + 0; mykk = kk - (q0 - h0); myct = h0; } \
    if (q1 >= kk && q1 - h1 < kk) { mybin = t * 4 + 1; mykk = kk - (q1 - h1); myct = h1; } \
    if (q2 >= kk && q2 - h2 < kk) { mybin = t * 4 + 2; mykk = kk - (q2 - h2); myct = h2; } \
    if (q3 >= kk && q3 - h3 < kk) { mybin = t * 4 + 3; mykk = kk - (q3 - h3); myct = h3; } \
    if (mybin >= 0) { ibc[0] = mybin; ibc[1] = mykk; ibc[3] = myct; }         \
  }

  // stats finalize + pass-0 radix scan share one barrier section
  if (t == 0) {
    float S = rs[0] + rs[1] + rs[2] + rs[3];
    float Q = rs[4] + rs[5] + rs[6] + rs[7];
    float mu = S / (float)LP;
    float var = Q / (float)LP - mu * mu;
    float inv = rsqrtf(var + 1e-5f);
    float sc = gma * inv;
    fbc[0] = sc;
    fbc[1] = bn_beta[h] - mu * sc;
    cnt = 0;
  }
  RADIX_SCAN();
  __syncthreads();  // ibc, fbc, cnt ready

  unsigned prefix = ((unsigned)ibc[0]) << 24;
  unsigned pm = 0xFF000000u;
  kk = ibc[1];
  const unsigned b0 = (unsigned)ibc[0];

  // compact the selected top-byte bin into cand[] (order-independent result)
  for (int i = t; i < LP; i += 256) {
    float x = xs[i];
    if ((KEY(x) >> 24) == b0) {
      int p = atomicAdd(&cnt, 1);
      cand[p] = x;
    }
  }
  __syncthreads();
  const int n1 = cnt;

  // passes 1..3 over the small candidate list (raw keys)
  for (int pass = 1; pass < 4; ++pass) {
    const int shift = 24 - 8 * pass;
    hist[t] = 0;
    __syncthreads();
    for (int i = t; i < n1; i += 256) {
      unsigned u = KEY(cand[i]);
      if ((u & pm) == prefix) atomicAdd(&hist[(u >> shift) & 255], 1);
    }
    __syncthreads();
    RADIX_SCAN();
    __syncthreads();
    prefix |= ((unsigned)ibc[0]) << shift;
    pm |= 255u << shift;
    kk = ibc[1];
  }
  const unsigned T = prefix;
  const int need_eq = kk;      // # needed among keys == T (derived)
  const int ceq = ibc[3];      // # keys == T (final-pass bin count)
  const bool tie = (ceq != need_eq);

  // mask + BN + sigmoid -> smp (fully overwrites the cand alias)
  const float sc = fbc[0], sh = fbc[1];
  for (int i = t; i < LP; i += 256) {
    float x = xs[i];
    unsigned u = KEY(x);
    bool sel = tie ? (u > T) : (u >= T);
    smp[i + 2] = sel ? 1.f / (1.f + __expf(-fmaf(x, sc, sh))) : 0.f;
  }
  if (t < 2) smp[t] = 0.f;
  if (t < 4) smp[NL + t] = 0.f;  // covers smp[2048..2051] for v4f reads
  __syncthreads();
  if (tie && t == 0) {  // rare: stable lowest-index-first like lax.top_k
    int taken = 0;
    for (int i = 0; i < LP && taken < need_eq; ++i) {
      float x = xs[i];
      if (KEY(x) == T) {
        smp[i + 2] = 1.f / (1.f + __expf(-fmaf(x, sc, sh)));
        ++taken;
      }
    }
  }
  __syncthreads();

  // 3-tap box sum, v4f output (in-register shifts from two aligned LDS v4f)
  const float cw = comb_w[h] * (1.0f / (float)KW);
  float* row = xi + (size_t)bh * NL;
#pragma unroll
  for (int q = 0; q < 2; ++q) {
    const int l = q * 1024 + t * 4;
    v4f a = *(const v4f*)&smp[l];
    v4f bsh = *(const v4f*)&smp[l + 4];
    v4f u1 = {a.y, a.z, a.w, bsh.x};
    v4f u2 = {a.z, a.w, bsh.x, bsh.y};
    v4f r = (a + u1 + u2);
    r.x *= cw; r.y *= cw; r.z *= cw; r.w *= cw;
    *(v4f*)&row[l] = r;
  }
#undef KEY
#undef RADIX_SCAN
}

// Kernel 3 (R17-verbatim): each thread owns one (b,l4) pair, computes the
// 8-head gate sum once, reuses it across 16 channels of coalesced
// src-load + plain store. ~45us, near the 268MB mixed-stream ceiling.
__global__ __launch_bounds__(256) void scale_gate(
    const float* __restrict__ src, const float* __restrict__ xi,
    const float* __restrict__ comb_b, float* __restrict__ out) {
  const int t = threadIdx.x;
  const int cchunk = blockIdx.x >> 7;               // 0..15, 16 channels each
  const int pairidx = (blockIdx.x & 127) * 256 + t; // 0..32767
  const int b = pairidx >> 9;                       // NL/4 = 512 l4 per b
  const int l4 = pairidx & 511;
  const float cb = comb_b[0];

  const v4f* xp = (const v4f*)(xi + (size_t)b * NH * NL) + l4;
  v4f g = xp[0];
#pragma unroll
  for (int h = 1; h < NH; ++h) g += xp[(size_t)h * (NL / 4)];

  const int c0 = cchunk * (NC / 16);
  const v4f* sp = (const v4f*)src + ((size_t)b * NC + c0) * (NL / 4) + l4;
  v4f* op = (v4f*)out + ((size_t)b * NC + c0) * (NL / 4) + l4;
#pragma unroll 4
  for (int c = 0; c < NC / 16; ++c) {
    v4f sv = sp[(size_t)c * (NL / 4)];
    v4f ov;
    ov.x = fmaf(sv.x, g.x, cb);
    ov.y = fmaf(sv.y, g.y, cb);
    ov.z = fmaf(sv.z, g.z, cb);
    ov.w = fmaf(sv.w, g.w, cb);
    op[(size_t)c * (NL / 4)] = ov;
  }
}

extern "C" void kernel_launch(void* const* d_in, const int* in_sizes, int n_in,
                              void* d_out, int out_size, void* d_ws, size_t ws_size,
                              hipStream_t stream) {
  const float* src = (const float*)d_in[0];
  const float* conv_w = (const float*)d_in[1];
  const float* conv_b = (const float*)d_in[2];
  const float* bn_gamma = (const float*)d_in[3];
  const float* bn_beta = (const float*)d_in[4];
  const float* comb_w = (const float*)d_in[5];
  const float* comb_b = (const float*)d_in[6];
  const int* kptr = (const int*)d_in[7];
  float* out = (float*)d_out;

  float* xi = (float*)d_ws;  // NB*NH*NL floats (4 MB)
  float* part = out;         // 32 MB scratch inside d_out: consumed by
                             // select_block, then overwritten by scale_gate

  conv_partial<<<dim3(2, NB, NCHUNK), 256, 0, stream>>>(src, conv_w, part);
  select_block<<<NB * NH, 256, 0, stream>>>(part, xi, conv_b, bn_gamma,
                                            bn_beta, comb_w, kptr);
  scale_gate<<<2048, 256, 0, stream>>>(src, xi, comb_b, out);
}